// Round 2
// baseline (6379.290 us; speedup 1.0000x reference)
//
#include <hip/hip_runtime.h>
#include <hip/hip_fp16.h>

// GInvariantLSTMLayer persistent-RNN, round 8.
// Backbone (r3/r6, validated): sc1 cache-bypass loads + sc1 write-through stores,
// zero fences, 2-deep x 16-fragment load pipeline with memory-clobbered vmcnt waits,
// two-level monotonic grid barrier. r7 (validated): weights in registers, MFMA loop
// reads zero LDS, cross-wave K reduction through bank-swizzled LDS.
// r8: L3 BROADCAST HALVED. r7 showed dur unchanged with LDS conflicts -92% -> the
// step is bound by the grid-wide h broadcast (nblocks x 256 KB = 64 MB/step from
// Infinity Cache). Now 128 blocks x 16 features (was 256 x 8): 32 MB/step. Weight
// set per lane doubles to 256 regs (AGPR-ized, proven by r7's 184-VGPR count at a
// 256+-reg working set); load pipeline byte-identical; acc narrowed to per-bt with
// scatter-after-group; h stores now 32 B contiguous (write-allocate 25%->50%).

typedef _Float16 f16x8 __attribute__((ext_vector_type(8)));
typedef float    f32x4 __attribute__((ext_vector_type(4)));
typedef unsigned long long u64;

static __device__ __forceinline__ float fast_sig(float x) {
  return 1.f / (1.f + __expf(-x));
}
static __device__ __forceinline__ float fast_tanh(float x) {
  x = fminf(15.f, fmaxf(-15.f, x));
  const float e = __expf(2.f * x);
  return (e - 1.f) / (e + 1.f);
}

static __device__ __forceinline__ void st_h16(void* p, float v) {
  const unsigned short b = __builtin_bit_cast(unsigned short, (_Float16)v);
  __hip_atomic_store((unsigned short*)p, b, __ATOMIC_RELAXED, __HIP_MEMORY_SCOPE_AGENT);
}
static __device__ __forceinline__ void st_h64(void* p, u64 v) {
  __hip_atomic_store((u64*)p, v, __ATOMIC_RELAXED, __HIP_MEMORY_SCOPE_AGENT);
}

// Packed h layout (r4-validated): element (n, j) at byte offset
//   ((n>>4)<<16) + ((j>>5)<<10) + ((n&15)<<6) + (((j>>3)&3)<<4) + ((j&7)<<1)
static __device__ __forceinline__ int h_off(int n, int j) {
  return ((n >> 4) << 16) + ((j >> 5) << 10) + ((n & 15) << 6) +
         (((j >> 3) & 3) << 4) + ((j & 7) << 1);
}

__global__ void __launch_bounds__(256) seq_sum_kernel(const float* __restrict__ X,
                                                      float* s_all) {
  const int gw   = (int)((blockIdx.x * blockDim.x + threadIdx.x) >> 6);
  const int lane = threadIdx.x & 63;
  const int n = gw >> 9, t = gw & 511;
  const float4* p = (const float4*)(X + ((size_t)gw << 10));
  float s = 0.f;
#pragma unroll
  for (int i = 0; i < 4; ++i) {
    const float4 v = p[lane + (i << 6)];
    s += (v.x + v.y) + (v.z + v.w);
  }
#pragma unroll
  for (int off = 32; off; off >>= 1) s += __shfl_xor(s, off);
  if (lane == 0) s_all[(t << 6) + n] = s;
}

__global__ void bar_init_kernel(unsigned* bar) {
  bar[threadIdx.x]       = 0u;
  bar[threadIdx.x + 256] = 0u;
  bar[threadIdx.x + 512] = 0u;
  bar[threadIdx.x + 768] = 0u;
}

// Two-level monotonic grid barrier; all ops relaxed agent-scope (L3-homed).
// 128 blocks: 8 groups x 16 blocks; root target 8*round.
static __device__ __forceinline__ void grid_barrier2(unsigned* bar, unsigned round,
                                                     int tid, int blk) {
  asm volatile("s_waitcnt vmcnt(0)" ::: "memory");  // write-through stores drained
  __syncthreads();
  if (tid == 0) {
    unsigned* grp  = bar + ((blk & 7) << 5);
    unsigned* root = bar + 512;
    const unsigned old =
        __hip_atomic_fetch_add(grp, 1u, __ATOMIC_RELAXED, __HIP_MEMORY_SCOPE_AGENT);
    if (old == 16u * round - 1u)
      __hip_atomic_fetch_add(root, 1u, __ATOMIC_RELAXED, __HIP_MEMORY_SCOPE_AGENT);
    const unsigned target = 8u * round;
    unsigned guard = 0;
    while (__hip_atomic_load(root, __ATOMIC_RELAXED, __HIP_MEMORY_SCOPE_AGENT) <
           target) {
      __builtin_amdgcn_s_sleep(1);
      if (++guard > (1u << 23)) break;  // anti-hang guard; never fires when resident
    }
  }
  __syncthreads();
}

// Issue 4 sc1 dwordx4 loads from one 4-KB window (one address pair, imm offsets).
#define LOAD4(d0, d1, d2, d3, addr)                                         \
  asm volatile("global_load_dwordx4 %0, %4, off sc1\n\t"                    \
               "global_load_dwordx4 %1, %4, off offset:1024 sc1\n\t"        \
               "global_load_dwordx4 %2, %4, off offset:2048 sc1\n\t"        \
               "global_load_dwordx4 %3, %4, off offset:3072 sc1"            \
               : "=v"(d0), "=v"(d1), "=v"(d2), "=v"(d3)                     \
               : "v"(addr)                                                  \
               : "memory")

// Wait until <= n vmem ops outstanding; ties all 16 fragments of the group so
// dependent MFMAs cannot hoist above; memory clobber pins all other mem ops.
#define WAITG(n, A)                                                         \
  asm volatile("s_waitcnt vmcnt(" #n ")"                                    \
               : "+v"(A[0]), "+v"(A[1]), "+v"(A[2]), "+v"(A[3]),            \
                 "+v"(A[4]), "+v"(A[5]), "+v"(A[6]), "+v"(A[7]),            \
                 "+v"(A[8]), "+v"(A[9]), "+v"(A[10]), "+v"(A[11]),          \
                 "+v"(A[12]), "+v"(A[13]), "+v"(A[14]), "+v"(A[15])         \
               :                                                            \
               : "memory")

// One K-group (16 K-chunks of 32) feeds 4 column tiles; weights from registers only.
#define KMATH(A)                                                            \
  _Pragma("unroll")                                                         \
  for (int i_ = 0; i_ < 16; ++i_) {                                         \
    acc[0] = __builtin_amdgcn_mfma_f32_16x16x32_f16(A[i_], Wr[i_][0],       \
                                                    acc[0], 0, 0, 0);       \
    acc[1] = __builtin_amdgcn_mfma_f32_16x16x32_f16(A[i_], Wr[i_][1],       \
                                                    acc[1], 0, 0, 0);       \
    acc[2] = __builtin_amdgcn_mfma_f32_16x16x32_f16(A[i_], Wr[i_][2],       \
                                                    acc[2], 0, 0, 0);       \
    acc[3] = __builtin_amdgcn_mfma_f32_16x16x32_f16(A[i_], Wr[i_][3],       \
                                                    acc[3], 0, 0, 0);       \
  }

// Scatter one batch-group's partials, bank-swizzled: 2-way max per ds_write_b32.
#define SCATTER(bt)                                                         \
  _Pragma("unroll")                                                         \
  for (int ct_ = 0; ct_ < 4; ++ct_) {                                       \
    const int kf_ = ct_ * 4 + (cc >> 2);                                    \
    _Pragma("unroll")                                                       \
    for (int v_ = 0; v_ < 4; ++v_) {                                        \
      const int n_ = (bt)*16 + (q << 2) + v_;                               \
      red[wave][n_][((kf_ ^ (n_ & 15)) << 2) + (cc & 3)] = acc[ct_][v_];    \
    }                                                                       \
  }

__global__ void __launch_bounds__(256, 1) ginv_lstm_persist(
    const float* __restrict__ lin_W, const float* __restrict__ inv_w,
    const float* __restrict__ inv_b, const float* __restrict__ lin_b,
    const float* s_all, const float* __restrict__ H0,
    _Float16* hb0, _Float16* hb1, unsigned* bar, float* out) {
  // red[0..3] used for the cross-wave K reduction; deliberately oversized (96 KB)
  // so a second block can never co-reside on the CU (LDS 98 KB > 160/2).
  __shared__ __align__(16) float red[6][64][64];
  __shared__ __align__(16) _Float16 hx[64][16];  // 2 KB h transpose buffer
  const int blk = blockIdx.x;
  const int tid = threadIdx.x;
  _Float16* hbuf[2] = {hb0, hb1};

  const int wave = tid >> 6;   // = K-quarter owner, and kf base in reduce phase
  const int lane = tid & 63;   // = batch row n in reduce phase
  const int q    = lane >> 4;
  const int cc   = lane & 15;

  // ---- stage this wave's weight slice fp32 -> fp16 REGISTERS (once) ----
  // Column c = ct*16+cc maps to (kf = c>>2, gate = c&3); element e of fragment
  // (kc, ct) = lin_W[g][blk*16+kf][wave*512 + kc*32 + q*8 + e].
  f16x8 Wr[16][4];
#pragma unroll
  for (int ct = 0; ct < 4; ++ct) {
    const int kf = ct * 4 + (cc >> 2), g = cc & 3;
    const float* wrow =
        lin_W + (((size_t)(g * 2048 + blk * 16 + kf)) << 11) + wave * 512 + q * 8;
#pragma unroll
    for (int kc = 0; kc < 16; ++kc) {
      const float4 va = *(const float4*)(wrow + kc * 32);
      const float4 vb = *(const float4*)(wrow + kc * 32 + 4);
      f16x8 f;
      f[0] = (_Float16)va.x; f[1] = (_Float16)va.y;
      f[2] = (_Float16)va.z; f[3] = (_Float16)va.w;
      f[4] = (_Float16)vb.x; f[5] = (_Float16)vb.y;
      f[6] = (_Float16)vb.z; f[7] = (_Float16)vb.w;
      Wr[kc][ct] = f;
    }
  }

  // ---- init h(0) into packed layout (write-through): 1024 elements/block ----
#pragma unroll
  for (int i = 0; i < 4; ++i) {
    const int idx = blk * 1024 + i * 256 + tid;
    st_h16((char*)hb0 + h_off(idx >> 11, idx & 2047), H0[idx]);
  }

  // ---- per-thread gate constants: thread finalizes (n=lane, kf=wave+4*kk) ----
  float iw[4][4], ibb[4][4];
#pragma unroll
  for (int kk = 0; kk < 4; ++kk) {
    const int Kg = blk * 16 + wave + (kk << 2);
#pragma unroll
    for (int g = 0; g < 4; ++g) {
      iw[kk][g]  = inv_w[(g << 11) + Kg];
      ibb[kk][g] = inv_b[(g << 11) + Kg] + lin_b[(g << 11) + Kg];
    }
  }

  unsigned round = 1;
  grid_barrier2(bar, round, tid, blk);  // h(0) staged grid-wide

  float cst[4] = {0.f, 0.f, 0.f, 0.f};

  // Fragment (bt, kc) of this wave: h[n = bt*16+cc][j = wave*512 + kc*32 + q*8 + e]
  // -> packed offset (bt<<16) + ((wave*16+kc)<<10) + (cc<<6) + (q<<4).
  const int ld_base = (wave << 14) + (cc << 6) + (q << 4);
  const int st_off = ((lane >> 4) << 16) + ((blk >> 1) << 10) + ((lane & 15) << 6) +
                     ((blk & 1) << 5);

  for (int t = 0; t < 512; ++t) {
    const char* hpb = (const char*)hbuf[t & 1] + ld_base;

    // s_all read issued BEFORE the pipeline: an older outstanding vmem op only
    // makes the group waits stricter (never looser).
    const float sv = s_all[(t << 6) + lane];

    f16x8 pa[16], pb[16];  // double-buffered prefetch: 32 fragments = 128 VGPRs
    f32x4 acc[4];          // per-batch-group accumulators (4 column tiles)

    // issue G0 (bt=0) -> pa, G1 (bt=1) -> pb   (16 loads each; 4 addr pairs/group)
#pragma unroll
    for (int w = 0; w < 4; ++w)
      LOAD4(pa[w * 4], pa[w * 4 + 1], pa[w * 4 + 2], pa[w * 4 + 3],
            hpb + (w << 12));
#pragma unroll
    for (int w = 0; w < 4; ++w)
      LOAD4(pb[w * 4], pb[w * 4 + 1], pb[w * 4 + 2], pb[w * 4 + 3],
            hpb + 65536 + (w << 12));

    WAITG(16, pa);            // G0 landed (G1 = newest 16 may be in flight)
#pragma unroll
    for (int ct = 0; ct < 4; ++ct) acc[ct] = (f32x4){0.f, 0.f, 0.f, 0.f};
    KMATH(pa);
#pragma unroll
    for (int w = 0; w < 4; ++w)  // issue G2 (bt=2) -> pa
      LOAD4(pa[w * 4], pa[w * 4 + 1], pa[w * 4 + 2], pa[w * 4 + 3],
            hpb + 131072 + (w << 12));
    SCATTER(0);

    WAITG(16, pb);            // G1 landed
#pragma unroll
    for (int ct = 0; ct < 4; ++ct) acc[ct] = (f32x4){0.f, 0.f, 0.f, 0.f};
    KMATH(pb);
#pragma unroll
    for (int w = 0; w < 4; ++w)  // issue G3 (bt=3) -> pb
      LOAD4(pb[w * 4], pb[w * 4 + 1], pb[w * 4 + 2], pb[w * 4 + 3],
            hpb + 196608 + (w << 12));
    SCATTER(1);

    WAITG(16, pa);            // G2 landed
#pragma unroll
    for (int ct = 0; ct < 4; ++ct) acc[ct] = (f32x4){0.f, 0.f, 0.f, 0.f};
    KMATH(pa);
    SCATTER(2);

    WAITG(0, pb);             // G3 landed
#pragma unroll
    for (int ct = 0; ct < 4; ++ct) acc[ct] = (f32x4){0.f, 0.f, 0.f, 0.f};
    KMATH(pb);
    SCATTER(3);

    __syncthreads();

    // ---- reduce 4 K-quarters + gates. Thread = (n = lane, kf = wave + 4*kk). ----
    float hnew[4];
#pragma unroll
    for (int kk = 0; kk < 4; ++kk) {
      const int kf  = wave + (kk << 2);
      const int off = (kf ^ (lane & 15)) << 2;
      f32x4 zz = *(const f32x4*)&red[0][lane][off];
#pragma unroll
      for (int w = 1; w < 4; ++w) zz += *(const f32x4*)&red[w][lane][off];
      const float zi = zz[0] + sv * iw[kk][0] + ibb[kk][0];
      const float zf = zz[1] + sv * iw[kk][1] + ibb[kk][1];
      const float zg = zz[2] + sv * iw[kk][2] + ibb[kk][2];
      const float zo = zz[3] + sv * iw[kk][3] + ibb[kk][3];
      const float ig = fast_sig(zi);
      const float fg = fast_sig(zf);
      const float gg = fast_tanh(zg);
      const float og = fast_sig(zo);
      const float cn = fg * cst[kk] + ig * gg;
      cst[kk] = cn;
      hnew[kk] = og * fast_tanh(cn);
    }

    // Transpose block's h slice through LDS (also at t=511, feeds the epilogue).
#pragma unroll
    for (int kk = 0; kk < 4; ++kk) hx[lane][wave + (kk << 2)] = (_Float16)hnew[kk];
    __syncthreads();
    if (t < 511 && tid < 64) {
      union { f16x8 v; u64 w[2]; } u0, u1;
      u0.v = *(const f16x8*)&hx[lane][0];
      u1.v = *(const f16x8*)&hx[lane][8];
      char* dst = (char*)hbuf[(t + 1) & 1] + st_off;
      st_h64(dst,      u0.w[0]);
      st_h64(dst + 8,  u0.w[1]);
      st_h64(dst + 16, u1.w[0]);
      st_h64(dst + 24, u1.w[1]);
    }
    ++round;
    grid_barrier2(bar, round, tid, blk);  // also orders s_all reads vs out (fallback)
  }

  // Epilogue: hx holds h(511); lane = batch row, features blk*16..blk*16+15.
  if (tid < 64) {
#pragma unroll
    for (int f = 0; f < 16; ++f)
      out[((blk * 16 + f) << 6) + lane] = (float)hx[lane][f];
  }
}

extern "C" void kernel_launch(void* const* d_in, const int* in_sizes, int n_in,
                              void* d_out, int out_size, void* d_ws, size_t ws_size,
                              hipStream_t stream) {
  const float* X     = (const float*)d_in[0];
  const float* H0    = (const float*)d_in[1];
  const float* inv_w = (const float*)d_in[2];
  const float* inv_b = (const float*)d_in[3];
  const float* lin_W = (const float*)d_in[4];
  const float* lin_b = (const float*)d_in[5];
  float* out = (float*)d_out;

  const size_t S_BYTES = 512 * 64 * 4;
  const size_t BAR_PAD = 4096;
  const size_t H_BYTES = 64 * 2048 * 2;
  const size_t NEED = S_BYTES + BAR_PAD + 2 * H_BYTES;

  float*    s_all;
  unsigned* bar;
  _Float16* hb[2];
  if (ws_size >= NEED) {
    char* ws = (char*)d_ws;
    s_all = (float*)ws;
    bar   = (unsigned*)(ws + S_BYTES);
    for (int i = 0; i < 2; ++i)
      hb[i] = (_Float16*)(ws + S_BYTES + BAR_PAD + (size_t)i * H_BYTES);
  } else {
    // Fallback: s_all in d_out (final out written after last barrier), bar + h
    // buffers in X's tail (X fully consumed by seq_sum_kernel first on-stream;
    // harness restores X before every launch).
    s_all = (float*)d_out;
    char* xt = (char*)d_in[0] + (size_t)64 * 512 * 1024 * 4 -
               (BAR_PAD + 2 * H_BYTES);
    bar = (unsigned*)xt;
    for (int i = 0; i < 2; ++i)
      hb[i] = (_Float16*)(xt + BAR_PAD + (size_t)i * H_BYTES);
  }

  seq_sum_kernel<<<8192, 256, 0, stream>>>(X, s_all);
  bar_init_kernel<<<1, 256, 0, stream>>>(bar);
  ginv_lstm_persist<<<128, 256, 0, stream>>>(lin_W, inv_w, inv_b, lin_b, s_all, H0,
                                             hb[0], hb[1], bar, out);
}

// Round 4
// 4078.822 us; speedup vs baseline: 1.5640x; 1.5640x over previous
//
#include <hip/hip_runtime.h>
#include <hip/hip_fp16.h>

// GInvariantLSTMLayer persistent-RNN, round 10.
// Backbone (r3/r6, validated): sc1 cache-bypass loads + sc1 write-through stores,
// zero fences, memory-clobbered vmcnt waits, two-level monotonic grid barrier.
// r7 (validated): weights in registers, MFMA loop reads zero LDS.
// r8 POST-MORTEM: halving total L3 traffic (128 blocks x 2x per-CU work) was 1.5x
// WORSE -> step time = B (barrier ~4.3us) + W (per-CU serial work ~4us), W scales
// 1:1 with per-CU work; aggregate L3 BW is NOT the limit.
// r9 (batch-split) CRASHED with a GPU memory fault. Audit: LOAD4's outputs were
// plain "=v"; the asm writes d0 in inst 1 but reads addr in insts 2-4, so without
// early-clobber the allocator may alias an output with the address pair ->
// clobbered address -> page fault (the r5 failure class). r6-r8 got lucky on
// regalloc; r9's changed live-range shape exposed it.
// r10: r9 + "=&v" early-clobber on all LOAD4 outputs. Structure unchanged:
// 256 blocks = 128 feature-groups x 2 batch-halves; each block 16 features x
// 32 batches; per-CU h-load stream halved to 128 KB/step (2 groups, 32 loads/wave);
// MFMA/wave stays 128 (= r7); weight regs 256/lane (AGPR-backed, r8-proven).

typedef _Float16 f16x8 __attribute__((ext_vector_type(8)));
typedef float    f32x4 __attribute__((ext_vector_type(4)));
typedef unsigned long long u64;

static __device__ __forceinline__ float fast_sig(float x) {
  return 1.f / (1.f + __expf(-x));
}
static __device__ __forceinline__ float fast_tanh(float x) {
  x = fminf(15.f, fmaxf(-15.f, x));
  const float e = __expf(2.f * x);
  return (e - 1.f) / (e + 1.f);
}

static __device__ __forceinline__ void st_h16(void* p, float v) {
  const unsigned short b = __builtin_bit_cast(unsigned short, (_Float16)v);
  __hip_atomic_store((unsigned short*)p, b, __ATOMIC_RELAXED, __HIP_MEMORY_SCOPE_AGENT);
}
static __device__ __forceinline__ void st_h64(void* p, u64 v) {
  __hip_atomic_store((u64*)p, v, __ATOMIC_RELAXED, __HIP_MEMORY_SCOPE_AGENT);
}

// Packed h layout (r4-validated): element (n, j) at byte offset
//   ((n>>4)<<16) + ((j>>5)<<10) + ((n&15)<<6) + (((j>>3)&3)<<4) + ((j&7)<<1)
static __device__ __forceinline__ int h_off(int n, int j) {
  return ((n >> 4) << 16) + ((j >> 5) << 10) + ((n & 15) << 6) +
         (((j >> 3) & 3) << 4) + ((j & 7) << 1);
}

__global__ void __launch_bounds__(256) seq_sum_kernel(const float* __restrict__ X,
                                                      float* s_all) {
  const int gw   = (int)((blockIdx.x * blockDim.x + threadIdx.x) >> 6);
  const int lane = threadIdx.x & 63;
  const int n = gw >> 9, t = gw & 511;
  const float4* p = (const float4*)(X + ((size_t)gw << 10));
  float s = 0.f;
#pragma unroll
  for (int i = 0; i < 4; ++i) {
    const float4 v = p[lane + (i << 6)];
    s += (v.x + v.y) + (v.z + v.w);
  }
#pragma unroll
  for (int off = 32; off; off >>= 1) s += __shfl_xor(s, off);
  if (lane == 0) s_all[(t << 6) + n] = s;
}

__global__ void bar_init_kernel(unsigned* bar) {
  bar[threadIdx.x]       = 0u;
  bar[threadIdx.x + 256] = 0u;
  bar[threadIdx.x + 512] = 0u;
  bar[threadIdx.x + 768] = 0u;
}

// Two-level monotonic grid barrier; all ops relaxed agent-scope (L3-homed).
// 256 blocks: 8 groups x 32 blocks; root target 8*round.  (r7 constants)
static __device__ __forceinline__ void grid_barrier2(unsigned* bar, unsigned round,
                                                     int tid, int blk) {
  asm volatile("s_waitcnt vmcnt(0)" ::: "memory");  // write-through stores drained
  __syncthreads();
  if (tid == 0) {
    unsigned* grp  = bar + ((blk & 7) << 5);
    unsigned* root = bar + 512;
    const unsigned old =
        __hip_atomic_fetch_add(grp, 1u, __ATOMIC_RELAXED, __HIP_MEMORY_SCOPE_AGENT);
    if (old == 32u * round - 1u)
      __hip_atomic_fetch_add(root, 1u, __ATOMIC_RELAXED, __HIP_MEMORY_SCOPE_AGENT);
    const unsigned target = 8u * round;
    unsigned guard = 0;
    while (__hip_atomic_load(root, __ATOMIC_RELAXED, __HIP_MEMORY_SCOPE_AGENT) <
           target) {
      __builtin_amdgcn_s_sleep(1);
      if (++guard > (1u << 23)) break;  // anti-hang guard; never fires when resident
    }
  }
  __syncthreads();
}

// Issue 4 sc1 dwordx4 loads from one 4-KB window (one address pair, imm offsets).
// "=&v" early-clobber: the asm writes d0 before its last read of addr, so outputs
// must NOT alias the address pair (r9 crash root cause).
#define LOAD4(d0, d1, d2, d3, addr)                                         \
  asm volatile("global_load_dwordx4 %0, %4, off sc1\n\t"                    \
               "global_load_dwordx4 %1, %4, off offset:1024 sc1\n\t"        \
               "global_load_dwordx4 %2, %4, off offset:2048 sc1\n\t"        \
               "global_load_dwordx4 %3, %4, off offset:3072 sc1"            \
               : "=&v"(d0), "=&v"(d1), "=&v"(d2), "=&v"(d3)                 \
               : "v"(addr)                                                  \
               : "memory")

// Wait until <= n vmem ops outstanding; ties all 16 fragments of the group so
// dependent MFMAs cannot hoist above; memory clobber pins all other mem ops.
#define WAITG(n, A)                                                         \
  asm volatile("s_waitcnt vmcnt(" #n ")"                                    \
               : "+v"(A[0]), "+v"(A[1]), "+v"(A[2]), "+v"(A[3]),            \
                 "+v"(A[4]), "+v"(A[5]), "+v"(A[6]), "+v"(A[7]),            \
                 "+v"(A[8]), "+v"(A[9]), "+v"(A[10]), "+v"(A[11]),          \
                 "+v"(A[12]), "+v"(A[13]), "+v"(A[14]), "+v"(A[15])         \
               :                                                            \
               : "memory")

// One K-group (16 K-chunks of 32) feeds 4 column tiles; weights from registers only.
#define KMATH(A)                                                            \
  _Pragma("unroll")                                                         \
  for (int i_ = 0; i_ < 16; ++i_) {                                         \
    acc[0] = __builtin_amdgcn_mfma_f32_16x16x32_f16(A[i_], Wr[i_][0],       \
                                                    acc[0], 0, 0, 0);       \
    acc[1] = __builtin_amdgcn_mfma_f32_16x16x32_f16(A[i_], Wr[i_][1],       \
                                                    acc[1], 0, 0, 0);       \
    acc[2] = __builtin_amdgcn_mfma_f32_16x16x32_f16(A[i_], Wr[i_][2],       \
                                                    acc[2], 0, 0, 0);       \
    acc[3] = __builtin_amdgcn_mfma_f32_16x16x32_f16(A[i_], Wr[i_][3],       \
                                                    acc[3], 0, 0, 0);       \
  }

// Scatter one batch-group's partials, bank-swizzled with key=(n&15)^(n>>4):
// write side 2-way max (free), read side balanced.
#define SCATTER(bt)                                                         \
  _Pragma("unroll")                                                         \
  for (int ct_ = 0; ct_ < 4; ++ct_) {                                       \
    const int kf_ = ct_ * 4 + (cc >> 2);                                    \
    _Pragma("unroll")                                                       \
    for (int v_ = 0; v_ < 4; ++v_) {                                        \
      const int n_  = (bt) * 16 + (q << 2) + v_;                            \
      const int key = (n_ & 15) ^ (n_ >> 4);                                \
      red[wave][n_][((kf_ ^ key) << 2) + (cc & 3)] = acc[ct_][v_];          \
    }                                                                       \
  }

__global__ void __launch_bounds__(256, 1) ginv_lstm_persist(
    const float* __restrict__ lin_W, const float* __restrict__ inv_w,
    const float* __restrict__ inv_b, const float* __restrict__ lin_b,
    const float* s_all, const float* __restrict__ H0,
    _Float16* hb0, _Float16* hb1, unsigned* bar, float* out) {
  // red[0..3] used for the cross-wave K reduction; deliberately oversized (96 KB)
  // so a second block can never co-reside on the CU (LDS 99 KB > 160/2).
  __shared__ __align__(16) float red[12][32][64];
  __shared__ __align__(16) _Float16 hx[32][16];  // 1 KB h transpose buffer
  const int blk = blockIdx.x;
  const int tid = threadIdx.x;
  _Float16* hbuf[2] = {hb0, hb1};

  const int fblk = blk & 127;  // feature group: features fblk*16 .. fblk*16+15
  const int nh   = blk >> 7;   // batch half:   batches  nh*32 .. nh*32+31

  const int wave = tid >> 6;   // K-quarter owner
  const int lane = tid & 63;
  const int q    = lane >> 4;
  const int cc   = lane & 15;

  // ---- stage this wave's weight slice fp32 -> fp16 REGISTERS (once) ----
  // Column c = ct*16+cc maps to (kf = c>>2, gate = c&3); element e of fragment
  // (kc, ct) = lin_W[g][fblk*16+kf][wave*512 + kc*32 + q*8 + e].
  f16x8 Wr[16][4];
#pragma unroll
  for (int ct = 0; ct < 4; ++ct) {
    const int kf = ct * 4 + (cc >> 2), g = cc & 3;
    const float* wrow =
        lin_W + (((size_t)(g * 2048 + fblk * 16 + kf)) << 11) + wave * 512 + q * 8;
#pragma unroll
    for (int kc = 0; kc < 16; ++kc) {
      const float4 va = *(const float4*)(wrow + kc * 32);
      const float4 vb = *(const float4*)(wrow + kc * 32 + 4);
      f16x8 f;
      f[0] = (_Float16)va.x; f[1] = (_Float16)va.y;
      f[2] = (_Float16)va.z; f[3] = (_Float16)va.w;
      f[4] = (_Float16)vb.x; f[5] = (_Float16)vb.y;
      f[6] = (_Float16)vb.z; f[7] = (_Float16)vb.w;
      Wr[kc][ct] = f;
    }
  }

  // ---- init h(0) into packed layout (write-through): 512 elements/block ----
  {
    int i0 = blk * 512 + tid;
    st_h16((char*)hb0 + h_off(i0 >> 11, i0 & 2047), H0[i0]);
    i0 += 256;
    st_h16((char*)hb0 + h_off(i0 >> 11, i0 & 2047), H0[i0]);
  }

  // ---- per-thread gate constants: thread finalizes
  //      (n = nh*32 + (lane&31), kf = wave + ((lane>>5)<<2) + kk*8), kk=0,1 ----
  const int nloc = lane & 31;
  const int nb   = lane >> 5;
  float iw[2][4], ibb[2][4];
#pragma unroll
  for (int kk = 0; kk < 2; ++kk) {
    const int kf = wave + (nb << 2) + (kk << 3);
    const int Kg = fblk * 16 + kf;
#pragma unroll
    for (int g = 0; g < 4; ++g) {
      iw[kk][g]  = inv_w[(g << 11) + Kg];
      ibb[kk][g] = inv_b[(g << 11) + Kg] + lin_b[(g << 11) + Kg];
    }
  }

  unsigned round = 1;
  grid_barrier2(bar, round, tid, blk);  // h(0) staged grid-wide

  float cst[2] = {0.f, 0.f};

  // Fragment (bt, kc): h[n = nh*32 + bt*16 + cc][j = wave*512 + kc*32 + q*8 + e]
  // -> packed byte ((nh*2+bt)<<16) + ((wave*16+kc)<<10) + (cc<<6) + (q<<4).
  const int ld_base = ((nh * 2) << 16) + (wave << 14) + (cc << 6) + (q << 4);
  // h store: lane ln (tid<32) writes n = nh*32+ln, features fblk*16..+15 = 32 B.
  const int st_off = ((nh * 2 + (tid >> 4)) << 16) + ((fblk >> 1) << 10) +
                     ((tid & 15) << 6) + ((fblk & 1) << 5);

  for (int t = 0; t < 512; ++t) {
    const char* hpb = (const char*)hbuf[t & 1] + ld_base;

    // s_all read issued BEFORE the pipeline: an older outstanding vmem op only
    // makes the group waits stricter (never looser).
    const float sv = s_all[(t << 6) + nh * 32 + nloc];

    f16x8 pa[16], pb[16];  // 2 groups x 16 fragments = 128 VGPRs
    f32x4 acc[4];          // 4 column tiles (16 features x 4 gates)

    // issue G0 (bt=0) -> pa, G1 (bt=1) -> pb   (16 loads each; 4 addr pairs/group)
#pragma unroll
    for (int w = 0; w < 4; ++w)
      LOAD4(pa[w * 4], pa[w * 4 + 1], pa[w * 4 + 2], pa[w * 4 + 3],
            hpb + (w << 12));
#pragma unroll
    for (int w = 0; w < 4; ++w)
      LOAD4(pb[w * 4], pb[w * 4 + 1], pb[w * 4 + 2], pb[w * 4 + 3],
            hpb + 65536 + (w << 12));

    WAITG(16, pa);            // G0 landed (G1 = newest 16 may be in flight)
#pragma unroll
    for (int ct = 0; ct < 4; ++ct) acc[ct] = (f32x4){0.f, 0.f, 0.f, 0.f};
    KMATH(pa);
    SCATTER(0);

    WAITG(0, pb);             // G1 landed
#pragma unroll
    for (int ct = 0; ct < 4; ++ct) acc[ct] = (f32x4){0.f, 0.f, 0.f, 0.f};
    KMATH(pb);
    SCATTER(1);

    __syncthreads();

    // ---- reduce 4 K-quarters + gates. Thread = (n = nloc, kf = wave+nb*4+kk*8).
    float hnew[2];
    const int key = (nloc & 15) ^ (nloc >> 4);
#pragma unroll
    for (int kk = 0; kk < 2; ++kk) {
      const int kf  = wave + (nb << 2) + (kk << 3);
      const int off = (kf ^ key) << 2;
      f32x4 zz = *(const f32x4*)&red[0][nloc][off];
#pragma unroll
      for (int w = 1; w < 4; ++w) zz += *(const f32x4*)&red[w][nloc][off];
      const float zi = zz[0] + sv * iw[kk][0] + ibb[kk][0];
      const float zf = zz[1] + sv * iw[kk][1] + ibb[kk][1];
      const float zg = zz[2] + sv * iw[kk][2] + ibb[kk][2];
      const float zo = zz[3] + sv * iw[kk][3] + ibb[kk][3];
      const float ig = fast_sig(zi);
      const float fg = fast_sig(zf);
      const float gg = fast_tanh(zg);
      const float og = fast_sig(zo);
      const float cn = fg * cst[kk] + ig * gg;
      cst[kk] = cn;
      hnew[kk] = og * fast_tanh(cn);
    }

    // Transpose block's h slice through LDS (also at t=511, feeds the epilogue).
#pragma unroll
    for (int kk = 0; kk < 2; ++kk)
      hx[nloc][wave + (nb << 2) + (kk << 3)] = (_Float16)hnew[kk];
    __syncthreads();
    if (t < 511 && tid < 32) {
      union { f16x8 v; u64 w[2]; } u0, u1;
      u0.v = *(const f16x8*)&hx[tid][0];
      u1.v = *(const f16x8*)&hx[tid][8];
      char* dst = (char*)hbuf[(t + 1) & 1] + st_off;
      st_h64(dst,      u0.w[0]);
      st_h64(dst + 8,  u0.w[1]);
      st_h64(dst + 16, u1.w[0]);
      st_h64(dst + 24, u1.w[1]);
    }
    ++round;
    grid_barrier2(bar, round, tid, blk);  // also orders s_all reads vs out (fallback)
  }

  // Epilogue: hx holds h(511); row = local batch, features fblk*16..fblk*16+15.
  if (tid < 32) {
#pragma unroll
    for (int f = 0; f < 16; ++f)
      out[((fblk * 16 + f) << 6) + nh * 32 + tid] = (float)hx[tid][f];
  }
}

extern "C" void kernel_launch(void* const* d_in, const int* in_sizes, int n_in,
                              void* d_out, int out_size, void* d_ws, size_t ws_size,
                              hipStream_t stream) {
  const float* X     = (const float*)d_in[0];
  const float* H0    = (const float*)d_in[1];
  const float* inv_w = (const float*)d_in[2];
  const float* inv_b = (const float*)d_in[3];
  const float* lin_W = (const float*)d_in[4];
  const float* lin_b = (const float*)d_in[5];
  float* out = (float*)d_out;

  const size_t S_BYTES = 512 * 64 * 4;
  const size_t BAR_PAD = 4096;
  const size_t H_BYTES = 64 * 2048 * 2;
  const size_t NEED = S_BYTES + BAR_PAD + 2 * H_BYTES;

  float*    s_all;
  unsigned* bar;
  _Float16* hb[2];
  if (ws_size >= NEED) {
    char* ws = (char*)d_ws;
    s_all = (float*)ws;
    bar   = (unsigned*)(ws + S_BYTES);
    for (int i = 0; i < 2; ++i)
      hb[i] = (_Float16*)(ws + S_BYTES + BAR_PAD + (size_t)i * H_BYTES);
  } else {
    // Fallback: s_all in d_out (final out written after last barrier), bar + h
    // buffers in X's tail (X fully consumed by seq_sum_kernel first on-stream;
    // harness restores X before every launch).
    s_all = (float*)d_out;
    char* xt = (char*)d_in[0] + (size_t)64 * 512 * 1024 * 4 -
               (BAR_PAD + 2 * H_BYTES);
    bar = (unsigned*)xt;
    for (int i = 0; i < 2; ++i)
      hb[i] = (_Float16*)(xt + BAR_PAD + (size_t)i * H_BYTES);
  }

  seq_sum_kernel<<<8192, 256, 0, stream>>>(X, s_all);
  bar_init_kernel<<<1, 256, 0, stream>>>(bar);
  ginv_lstm_persist<<<256, 256, 0, stream>>>(lin_W, inv_w, inv_b, lin_b, s_all, H0,
                                             hb[0], hb[1], bar, out);
}